// Round 3
// baseline (138.572 us; speedup 1.0000x reference)
//
#include <hip/hip_runtime.h>

#define H_DIM 256
#define N2D   32
#define L_SEQ 4096
#define B_SZ  16
#define L_C   128
#define N_C   32
#define KPAD  136

typedef short short8 __attribute__((ext_vector_type(8)));
typedef short short4v __attribute__((ext_vector_type(4)));
typedef float f32x4  __attribute__((ext_vector_type(4)));
typedef unsigned short ushort;

__device__ __forceinline__ ushort f2bf(float f) {
  unsigned int u = __float_as_uint(f);
  u = (u + 0x7fffu + ((u >> 16) & 1u)) >> 16;
  return (ushort)u;
}
__device__ __forceinline__ float bf2f(ushort s) {
  return __uint_as_float(((unsigned int)s) << 16);
}

// parK floats: [0..8191]=lam128_re [8192..16383]=lam128_im [16384..49151]=K[h][d]
__global__ __launch_bounds__(128) void k_prep(
    const float* __restrict__ log_dt, const float* __restrict__ log_A_real,
    const float* __restrict__ A_imag, const float* __restrict__ C_re,
    const float* __restrict__ C_im, float* __restrict__ parK,
    ushort* __restrict__ Mb, ushort* __restrict__ Lb) {
  int h = blockIdx.x;
  int t = threadIdx.x;  // 128
  __shared__ float sdre[32], sdim[32], scdr[32], scdi[32], slr[32], sli[32];
  if (t < 32) {
    int i = h * 32 + t;
    float dt = expf(log_dt[h]);
    float ar = -expf(log_A_real[i]);
    float ai = A_imag[i];
    float dre = ar * dt, dim = ai * dt;
    float er = expf(dre), sn, cs;
    sincosf(dim, &sn, &cs);
    float lr = er * cs, li = er * sn;
    float nr = lr - 1.f, ni = li;
    float inv = 1.f / (ar * ar + ai * ai);
    float tr = (nr * ar + ni * ai) * inv, ti = (ni * ar - nr * ai) * inv;
    float cdr = C_re[i] * tr - C_im[i] * ti;
    float cdi = C_re[i] * ti + C_im[i] * tr;
    sdre[t] = dre; sdim[t] = dim; scdr[t] = cdr; scdi[t] = cdi;
    slr[t] = lr; sli[t] = li;
    float e1 = expf(128.f * dre), ph = 128.f * dim;
    sincosf(ph, &sn, &cs);
    parK[i] = e1 * cs;
    parK[8192 + i] = e1 * sn;
  }
  __syncthreads();
  float ksum = 0.f;
  float tf = (float)t;
  for (int n = 0; n < 32; ++n) {
    float e = expf(tf * sdre[n]);
    float sn, cs;
    sincosf(tf * sdim[n], &sn, &cs);
    float pr = e * cs, pi = e * sn;  // lam^t
    ksum = fmaf(scdr[n], pr, fmaf(-scdi[n], pi, ksum));
    Lb[((size_t)h * 64 + 2 * n) * 128 + (127 - t)] = f2bf(pr);
    Lb[((size_t)h * 64 + 2 * n + 1) * 128 + (127 - t)] = f2bf(pi);
    float plr = pr * slr[n] - pi * sli[n];
    float pli = pr * sli[n] + pi * slr[n];  // lam^{t+1}
    Mb[((size_t)h * 128 + t) * 64 + 2 * n] =
        f2bf(2.f * (scdr[n] * plr - scdi[n] * pli));
    Mb[((size_t)h * 128 + t) * 64 + 2 * n + 1] =
        f2bf(-2.f * (scdr[n] * pli + scdi[n] * plr));
  }
  parK[16384 + h * 128 + t] = 2.f * ksum;
}

// T[h][l'][j] = (l'>=j) ? K[l'-j] + (l'==j)*D[h] : 0   (bf16)
__global__ void k_prep_T(const float* __restrict__ parK,
                         const float* __restrict__ Dp, ushort* __restrict__ T) {
  int idx = blockIdx.x * 256 + threadIdx.x;  // 4,194,304
  int h = idx >> 14;
  int rest = idx & 16383;
  int r = rest >> 7, j = rest & 127;
  int d = r - j;
  float v = 0.f;
  if (d >= 0) {
    v = parK[16384 + (h << 7) + d];
    if (d == 0) v += Dp[h];
  }
  T[idx] = f2bf(v);
}

// Repack W1*gamma / W2 into bf16 fragment order
__global__ void k_convw(const float* __restrict__ W1, const float* __restrict__ W2,
                        const float* __restrict__ gam,
                        ushort* __restrict__ w1f, ushort* __restrict__ w2f) {
  int i = blockIdx.x * 256 + threadIdx.x;  // 16384 threads
  int mat = i >> 13;
  int fi = i & 8191;  // ((kk*16+g)*64 + l)
  int l = fi & 63;
  int gk = fi >> 6;
  int g = gk & 15, kk = gk >> 4;
  int srow = g * 16 + (l & 15);
  int scol = kk * 32 + ((l >> 4) << 3);
  const float* W = mat ? W2 : W1;
  ushort* out = mat ? w2f : w1f;
  short8 v;
#pragma unroll
  for (int e = 0; e < 8; ++e) {
    float w = W[(size_t)srow * 256 + scol + e];
    if (!mat) w *= gam[scol + e];
    v[e] = (short)f2bf(w);
  }
  *(short8*)&out[(size_t)fi * 8] = v;
}

// cs1[o] = sum_h bf16(W1[o,h]*g[h]);  b1p[o] = b1[o] + sum_h W1[o,h]*bet[h]
__global__ __launch_bounds__(256) void k_wprep(
    const float* __restrict__ W1, const float* __restrict__ gam,
    const float* __restrict__ bet, const float* __restrict__ b1,
    float* __restrict__ cs1, float* __restrict__ b1p) {
  int o = blockIdx.x, t = threadIdx.x;
  float w = W1[(size_t)o * 256 + t];
  __shared__ float ra[256], rb[256];
  ra[t] = bf2f(f2bf(w * gam[t]));
  rb[t] = w * bet[t];
  __syncthreads();
  for (int s = 128; s > 0; s >>= 1) {
    if (t < s) { ra[t] += ra[t + s]; rb[t] += rb[t + s]; }
    __syncthreads();
  }
  if (t == 0) { cs1[o] = ra[0]; b1p[o] = b1[o] + rb[0]; }
}

// x (B,L,H) fp32 -> U (H, B*L) bf16
__global__ __launch_bounds__(256) void k_xT(const float* __restrict__ x,
                                            ushort* __restrict__ U) {
  int blk = blockIdx.x;  // 2048
  int b = blk >> 7;
  int l0 = (blk & 127) << 5;
  int t = threadIdx.x;
  __shared__ float tile[32][257];
#pragma unroll 8
  for (int r = 0; r < 32; ++r)
    tile[r][t] = x[((size_t)b * L_SEQ + l0 + r) * H_DIM + t];
  __syncthreads();
  int li0 = (t & 7) * 4;
  int hs = t >> 3;
#pragma unroll
  for (int pass = 0; pass < 8; ++pass) {
    int h = pass * 32 + hs;
    short4v v;
#pragma unroll
    for (int j = 0; j < 4; ++j) v[j] = (short)f2bf(tile[li0 + j][h]);
    *(short4v*)&U[(size_t)h * 65536 + (size_t)b * L_SEQ + l0 + li0] = v;
  }
}

// per-(h, ct) chunk-local states + exclusive scan over that ct-tile's 4 b's.
__global__ __launch_bounds__(256, 3) void k_states(
    const ushort* __restrict__ U, const ushort* __restrict__ Lb,
    const float* __restrict__ parK, ushort* __restrict__ stg) {
  int wgid = (blockIdx.x & 7) * 128 + (blockIdx.x >> 3);  // bijective, 1024
  int h = wgid >> 2, ct = wgid & 3;
  int t = threadIdx.x;
  int lane = t & 63, wid = t >> 6;
  int wm = wid & 1, wn = wid >> 1;
  int lr_ = lane & 15, lk = (lane >> 4) << 3;
  __shared__ ushort Bt[128][KPAD];
  __shared__ ushort sts[128][64];  // b-XOR swizzled state tile (local b)
#pragma unroll
  for (int q = 0; q < 8; ++q) {
    int idx = q * 256 + t;
    int cc = idx >> 4, seg = idx & 15;
    int col = ct * 128 + cc;
    int b = col >> 5, c = col & 31;
    *(short8*)&Bt[cc][seg * 8] = *(const short8*)&U[
        (size_t)h * 65536 + (size_t)b * L_SEQ + c * L_C + seg * 8];
  }
  __syncthreads();
  f32x4 acc[4][2];
#pragma unroll
  for (int m = 0; m < 4; ++m)
#pragma unroll
    for (int n = 0; n < 2; ++n) acc[m][n] = (f32x4){0.f, 0.f, 0.f, 0.f};
#pragma unroll
  for (int ks = 0; ks < 4; ++ks) {
    int k0 = ks * 32;
    short8 a[4], bfr[2];
#pragma unroll
    for (int m = 0; m < 4; ++m)
      a[m] = *(const short8*)&Bt[wm * 64 + m * 16 + lr_][k0 + lk];
#pragma unroll
    for (int n = 0; n < 2; ++n)
      bfr[n] = *(const short8*)&Lb[
          ((size_t)h * 64 + wn * 32 + n * 16 + lr_) * 128 + k0 + lk];
#pragma unroll
    for (int m = 0; m < 4; ++m)
#pragma unroll
      for (int n = 0; n < 2; ++n)
        acc[m][n] = __builtin_amdgcn_mfma_f32_16x16x32_bf16(a[m], bfr[n],
                                                            acc[m][n], 0, 0, 0);
  }
#pragma unroll
  for (int m = 0; m < 4; ++m)
#pragma unroll
    for (int n = 0; n < 2; ++n)
#pragma unroll
      for (int jj = 0; jj < 4; ++jj) {
        int rowl = wm * 64 + m * 16 + (lane >> 4) * 4 + jj;  // local 0..127
        int col2n = wn * 32 + n * 16 + (lane & 15);
        int sw = ((rowl >> 5) & 7) << 3;
        sts[rowl][col2n ^ sw] = f2bf(acc[m][n][jj]);
      }
  __syncthreads();
  // ---- exclusive scan over this ct-tile's 4 batches ----
  if (t < 128) {
    uint* stp = (uint*)stg;
    int n = t & 31, bl = t >> 5;  // local b 0..3
    int b = ct * 4 + bl;          // global b
    float Lr = parK[h * 32 + n], Li = parK[8192 + h * 32 + n];
    int sw = (bl & 7) << 3;
    int cre = (2 * n) ^ sw;
    float cr = 0.f, ci = 0.f;
#pragma unroll
    for (int c = 0; c < N_C; ++c) {
      int rowl = bl * 32 + c;
      uint v = *(const uint*)&sts[rowl][cre];
      float fr = bf2f((ushort)(v & 0xffff));
      float fi = bf2f((ushort)(v >> 16));
      stp[(((size_t)b * H_DIM + h) * N_C + c) * 32 + n] =
          (uint)f2bf(cr) | ((uint)f2bf(ci) << 16);
      float nr_ = fmaf(Lr, cr, fmaf(-Li, ci, fr));
      float ni_ = fmaf(Lr, ci, fmaf(Li, cr, fi));
      cr = nr_; ci = ni_;
    }
  }
}

// y[l', bc] = M @ s_init + T @ u per (h, chunk); written IN PLACE over U.
__global__ __launch_bounds__(256, 2) void k_y(
    const ushort* __restrict__ Mb, const ushort* __restrict__ T,
    const ushort* __restrict__ st, ushort* __restrict__ U) {
  int wgid = (blockIdx.x & 7) * 128 + (blockIdx.x >> 3);  // bijective, 1024
  int h = wgid >> 2, ct = wgid & 3;
  int t = threadIdx.x;
  int lane = t & 63, wid = t >> 6;
  int wm = wid & 1, wn = wid >> 1;
  int lr_ = lane & 15, lk = (lane >> 4) << 3;
  __shared__ ushort A_lds[128][KPAD];
  __shared__ ushort Bt[128][KPAD];
  f32x4 acc[4][4];
#pragma unroll
  for (int m = 0; m < 4; ++m)
#pragma unroll
    for (int n = 0; n < 4; ++n) acc[m][n] = (f32x4){0.f, 0.f, 0.f, 0.f};
  // ---- phase 1: K=64, A<-M, Bt<-states ----
#pragma unroll
  for (int q = 0; q < 4; ++q) {
    int idx = q * 256 + t;
    int r = idx >> 3, seg = idx & 7;
    *(short8*)&A_lds[r][seg * 8] =
        *(const short8*)&Mb[((size_t)h * 128 + r) * 64 + seg * 8];
    int col = ct * 128 + r;
    int b = col >> 5, c = col & 31;
    *(short8*)&Bt[r][seg * 8] = *(const short8*)&st[
        (((size_t)b * H_DIM + h) * N_C + c) * 64 + seg * 8];
  }
  __syncthreads();
#pragma unroll
  for (int ks = 0; ks < 2; ++ks) {
    int k0 = ks * 32;
    short8 a[4], bfr[4];
#pragma unroll
    for (int m = 0; m < 4; ++m)
      a[m] = *(const short8*)&Bt[wm * 64 + m * 16 + lr_][k0 + lk];
#pragma unroll
    for (int n = 0; n < 4; ++n)
      bfr[n] = *(const short8*)&A_lds[wn * 64 + n * 16 + lr_][k0 + lk];
#pragma unroll
    for (int m = 0; m < 4; ++m)
#pragma unroll
      for (int n = 0; n < 4; ++n)
        acc[m][n] = __builtin_amdgcn_mfma_f32_16x16x32_bf16(a[m], bfr[n],
                                                            acc[m][n], 0, 0, 0);
  }
  __syncthreads();
  // ---- phase 2: K=128, A<-T, Bt<-U ----
#pragma unroll
  for (int q = 0; q < 8; ++q) {
    int idx = q * 256 + t;
    int r = idx >> 4, seg = idx & 15;
    *(short8*)&A_lds[r][seg * 8] =
        *(const short8*)&T[((size_t)h * 128 + r) * 128 + seg * 8];
    int col = ct * 128 + r;
    int b = col >> 5, c = col & 31;
    *(short8*)&Bt[r][seg * 8] = *(const short8*)&U[
        (size_t)h * 65536 + (size_t)b * L_SEQ + c * L_C + seg * 8];
  }
  __syncthreads();
#pragma unroll
  for (int ks = 0; ks < 4; ++ks) {
    int k0 = ks * 32;
    short8 a[4], bfr[4];
#pragma unroll
    for (int m = 0; m < 4; ++m)
      a[m] = *(const short8*)&Bt[wm * 64 + m * 16 + lr_][k0 + lk];
#pragma unroll
    for (int n = 0; n < 4; ++n)
      bfr[n] = *(const short8*)&A_lds[wn * 64 + n * 16 + lr_][k0 + lk];
#pragma unroll
    for (int m = 0; m < 4; ++m)
#pragma unroll
      for (int n = 0; n < 4; ++n)
        acc[m][n] = __builtin_amdgcn_mfma_f32_16x16x32_bf16(a[m], bfr[n],
                                                            acc[m][n], 0, 0, 0);
  }
  // ---- stage y tile into LDS (A_lds dead), then vectorized store ----
  __syncthreads();
#pragma unroll
  for (int m = 0; m < 4; ++m) {
    int rowl = wm * 64 + m * 16 + (lane >> 4) * 4;
#pragma unroll
    for (int jj = 0; jj < 4; ++jj) {
      int row = rowl + jj;
#pragma unroll
      for (int n = 0; n < 4; ++n) {
        int lp = wn * 64 + n * 16 + (lane & 15);
        A_lds[row][lp] = f2bf(acc[m][n][jj]);
      }
    }
  }
  __syncthreads();
#pragma unroll
  for (int q = 0; q < 8; ++q) {
    int idx = q * 256 + t;
    int r = idx >> 4, seg = idx & 15;
    int col = ct * 128 + r;
    int b = col >> 5, c = col & 31;
    *(short8*)&U[(size_t)h * 65536 + (size_t)b * L_SEQ + c * L_C + seg * 8] =
        *(const short8*)&A_lds[r][seg * 8];
  }
}

// U (H, B*L) -> Y (B*L, H) bf16 + per-row LayerNorm stats (mu, rsigma).
// Transpose tile 32 rows x 256 h; stats code identical to prior fused LN
// (same summation order -> bit-identical mu/rs).
__global__ __launch_bounds__(512) void k_yT(const ushort* __restrict__ U,
                                            ushort* __restrict__ Y,
                                            float2* __restrict__ murs) {
  int wg = (blockIdx.x & 7) * 256 + (blockIdx.x >> 3);  // XCD-chunked, 2048
  int m0 = wg << 5;
  int t = threadIdx.x;
  __shared__ __attribute__((aligned(16))) ushort sm[8192];  // 16 KiB
  int hseg = t >> 2, l4 = t & 3;
#pragma unroll
  for (int p = 0; p < 2; ++p) {
    int h = p * 128 + hseg;
    short8 v = *(const short8*)&U[(size_t)h * 65536 + m0 + l4 * 8];
#pragma unroll
    for (int e = 0; e < 8; ++e) {
      int m = l4 * 8 + e;
      int byte = m * 512 + ((h * 2) ^ ((e ^ l4) << 4));
      sm[byte >> 1] = (ushort)v[e];
    }
  }
  __syncthreads();
  // ---- LN stats (verbatim from fused version) ----
  {
    int row = t >> 4, c15 = t & 15;
    int fr = ((row & 7) ^ ((row >> 3) & 7)) << 4;
    float s = 0.f, s2 = 0.f;
#pragma unroll
    for (int e = 0; e < 2; ++e) {
      int byte = row * 512 + (((c15 + e * 16) * 16) ^ fr);
      short8 v = *(const short8*)&sm[byte >> 1];
#pragma unroll
      for (int j = 0; j < 8; ++j) {
        float f = bf2f((ushort)v[j]);
        s += f;
        s2 = fmaf(f, f, s2);
      }
    }
#pragma unroll
    for (int d = 1; d < 16; d <<= 1) {
      s += __shfl_xor(s, d);
      s2 += __shfl_xor(s2, d);
    }
    if (c15 == 0) {
      float mu = s * (1.f / 256.f);
      float var = fmaf(s2, 1.f / 256.f, -mu * mu);
      murs[m0 + row] = (float2){mu, rsqrtf(var + 1e-5f)};
    }
  }
  // ---- coalesced store of transposed tile ----
#pragma unroll
  for (int q = 0; q < 2; ++q) {
    int idx = q * 512 + t;
    int r = idx >> 5, cseg = idx & 31;
    int fr = ((r & 7) ^ ((r >> 3) & 7)) << 4;
    short8 v = *(const short8*)&sm[(r * 512 + ((cseg * 16) ^ fr)) >> 1];
    *(short8*)&Y[(size_t)(m0 + r) * 256 + cseg * 8] = v;
  }
}

// LN-corrected MLP as a clean 128-row GEMM: coalesced Y staging (no transpose,
// no LN phase), 3 barriers, 512 blocks (weight L2 traffic back to 256 MB).
__global__ __launch_bounds__(512, 4) void k_mlp(
    const ushort* __restrict__ Y, const float2* __restrict__ murs,
    const ushort* __restrict__ w1f, const ushort* __restrict__ w2f,
    const float* __restrict__ cs1, const float* __restrict__ b1p,
    const float* __restrict__ b2, const float* __restrict__ xres,
    float* __restrict__ outp) {
  int wg = (blockIdx.x & 7) * 64 + (blockIdx.x >> 3);  // XCD-chunked, 512
  int m0 = wg << 7;  // 128 rows of (B*L)
  int t = threadIdx.x;
  int lane = t & 63, wid = t >> 6;
  int wm = wid & 1, wn = wid >> 1;
  int lr_ = lane & 15, lk = (lane >> 4) << 3;
  __shared__ __attribute__((aligned(16))) ushort smem[32768];  // 64 KiB
  __shared__ float mu_s[128], rs_s[128];
  // ---- stage Y tile (coalesced, XOR-swizzled) + murs ----
#pragma unroll
  for (int q = 0; q < 8; ++q) {
    int idx = q * 512 + t;
    int r = idx >> 5, cseg = idx & 31;
    short8 v = *(const short8*)&Y[(size_t)(m0 + r) * 256 + cseg * 8];
    int byte = r * 512 + ((cseg * 16) ^ ((r & 7) << 4));
    *(short8*)&smem[byte >> 1] = v;
  }
  if (t < 128) {
    float2 mr = murs[m0 + t];
    mu_s[t] = mr.x;
    rs_s[t] = mr.y;
  }
  __syncthreads();
  // ---- GEMM1: acc = y @ (W1*g)^T ----
  f32x4 acc[4][4];
#pragma unroll
  for (int m = 0; m < 4; ++m)
#pragma unroll
    for (int n = 0; n < 4; ++n) acc[m][n] = (f32x4){0.f, 0.f, 0.f, 0.f};
#pragma unroll
  for (int kabs = 0; kabs < 8; ++kabs) {
    short8 af[4], bfr[4];
#pragma unroll
    for (int n = 0; n < 4; ++n)
      bfr[n] = *(const short8*)&w1f[(((size_t)kabs * 16 + wn * 4 + n) * 64 +
                                     lane) * 8];
#pragma unroll
    for (int m = 0; m < 4; ++m) {
      int row = wm * 64 + m * 16 + lr_;
      int byte = row * 512 + ((((kabs * 32 + lk) << 1)) ^ ((row & 7) << 4));
      af[m] = *(const short8*)&smem[byte >> 1];
    }
#pragma unroll
    for (int m = 0; m < 4; ++m)
#pragma unroll
      for (int n = 0; n < 4; ++n)
        acc[m][n] = __builtin_amdgcn_mfma_f32_16x16x32_bf16(af[m], bfr[n],
                                                            acc[m][n], 0, 0, 0);
  }
  __syncthreads();  // yt dead; c_s overlays
  // ---- epilogue 1: LN-correct + bias + relu -> bf16 -> swizzled c_s ----
  int prow = (lane >> 4) << 2;
  int pcol = lane & 15;
#pragma unroll
  for (int n = 0; n < 4; ++n) {
    int gcol = wn * 64 + n * 16 + pcol;
    float c1v = cs1[gcol], b1v = b1p[gcol];
#pragma unroll
    for (int m = 0; m < 4; ++m) {
      int rbase = wm * 64 + m * 16 + prow;
#pragma unroll
      for (int j = 0; j < 4; ++j) {
        int row = rbase + j;
        float v = fmaxf(
            fmaf(rs_s[row], acc[m][n][j] - mu_s[row] * c1v, b1v), 0.f);
        int byte = ((row << 9) + (gcol << 1)) ^ ((row & 7) << 4);
        smem[byte >> 1] = f2bf(v);
        acc[m][n][j] = 0.f;  // re-zero for GEMM2
      }
    }
  }
  __syncthreads();
  // ---- GEMM2: acc = C1 @ W2^T ----
#pragma unroll
  for (int kabs = 0; kabs < 8; ++kabs) {
    short8 af[4], bfr[4];
#pragma unroll
    for (int n = 0; n < 4; ++n)
      bfr[n] = *(const short8*)&w2f[(((size_t)kabs * 16 + wn * 4 + n) * 64 +
                                     lane) * 8];
#pragma unroll
    for (int m = 0; m < 4; ++m) {
      int row = wm * 64 + m * 16 + lr_;
      int byte = ((row << 9) + ((kabs * 32 + lk) << 1)) ^ ((row & 7) << 4);
      af[m] = *(const short8*)&smem[byte >> 1];
    }
#pragma unroll
    for (int m = 0; m < 4; ++m)
#pragma unroll
      for (int n = 0; n < 4; ++n)
        acc[m][n] = __builtin_amdgcn_mfma_f32_16x16x32_bf16(af[m], bfr[n],
                                                            acc[m][n], 0, 0, 0);
  }
  // ---- epilogue 2: bias+relu + residual, fp32 out (direct) ----
  float bv2[4];
#pragma unroll
  for (int n = 0; n < 4; ++n) bv2[n] = b2[wn * 64 + n * 16 + pcol];
#pragma unroll
  for (int m = 0; m < 4; ++m) {
#pragma unroll
    for (int j = 0; j < 4; ++j) {
      int grow = m0 + wm * 64 + m * 16 + prow + j;
      size_t rb = (size_t)grow * 256;
#pragma unroll
      for (int n = 0; n < 4; ++n) {
        int gcol = wn * 64 + n * 16 + pcol;
        float v = fmaxf(acc[m][n][j] + bv2[n], 0.f);
        outp[rb + gcol] = xres[rb + gcol] + v;
      }
    }
  }
}

extern "C" void kernel_launch(void* const* d_in, const int* in_sizes, int n_in,
                              void* d_out, int out_size, void* d_ws, size_t ws_size,
                              hipStream_t stream) {
  const float* x          = (const float*)d_in[0];
  const float* log_dt     = (const float*)d_in[1];
  const float* log_A_real = (const float*)d_in[2];
  const float* A_imag     = (const float*)d_in[3];
  const float* C_re       = (const float*)d_in[4];
  const float* C_im       = (const float*)d_in[5];
  const float* Dp         = (const float*)d_in[6];
  const float* ln_g       = (const float*)d_in[7];
  const float* ln_b       = (const float*)d_in[8];
  const float* W1         = (const float*)d_in[9];
  const float* b1         = (const float*)d_in[10];
  const float* W2         = (const float*)d_in[11];
  const float* b2         = (const float*)d_in[12];

  char* ws = (char*)d_ws;
  float* parK = (float*)ws;                       // 192 KiB
  float* cs1  = (float*)(ws + 0x30000);           // 1 KiB
  float* b1p  = (float*)(ws + 0x30400);           // 1 KiB
  ushort* w1f = (ushort*)(ws + 0x40000);          // 128 KiB (fragment order)
  ushort* w2f = (ushort*)(ws + 0x60000);          // 128 KiB (fragment order)
  ushort* Mb  = (ushort*)(ws + 0x80000);          // 4 MiB
  ushort* Lb  = (ushort*)(ws + 0x480000);         // 4 MiB
  ushort* Tb  = (ushort*)(ws + 0x880000);         // 8 MiB
  ushort* st  = (ushort*)(ws + 0x1080000);        // 16 MiB (scanned states)
  ushort* U   = (ushort*)(ws + 0x2080000);        // 32 MiB (y written in place)
  // Y overlays Mb..st (all dead after k_y): exactly 32 MiB.
  ushort* Yb  = (ushort*)(ws + 0x80000);
  float2* murs = (float2*)(ws + 0x4080000);       // 512 KiB

  k_prep<<<256, 128, 0, stream>>>(log_dt, log_A_real, A_imag, C_re, C_im,
                                  parK, Mb, Lb);
  k_prep_T<<<16384, 256, 0, stream>>>(parK, Dp, Tb);
  k_convw<<<64, 256, 0, stream>>>(W1, W2, ln_g, w1f, w2f);
  k_wprep<<<256, 256, 0, stream>>>(W1, ln_g, ln_b, b1, cs1, b1p);
  k_xT<<<2048, 256, 0, stream>>>(x, U);
  k_states<<<1024, 256, 0, stream>>>(U, Lb, parK, st);
  k_y<<<1024, 256, 0, stream>>>(Mb, Tb, st, U);
  k_yT<<<2048, 512, 0, stream>>>(U, Yb, murs);
  k_mlp<<<512, 512, 0, stream>>>(Yb, murs, w1f, w2f, cs1, b1p, b2, x,
                                 (float*)d_out);
}

// Round 4
// 110.601 us; speedup vs baseline: 1.2529x; 1.2529x over previous
//
#include <hip/hip_runtime.h>

#define H_DIM 256
#define N2D   32
#define L_SEQ 4096
#define B_SZ  16
#define L_C   128
#define N_C   32
#define KPAD  136

typedef short short8 __attribute__((ext_vector_type(8)));
typedef short short4v __attribute__((ext_vector_type(4)));
typedef float f32x4  __attribute__((ext_vector_type(4)));
typedef unsigned short ushort;

__device__ __forceinline__ ushort f2bf(float f) {
  unsigned int u = __float_as_uint(f);
  u = (u + 0x7fffu + ((u >> 16) & 1u)) >> 16;
  return (ushort)u;
}
__device__ __forceinline__ float bf2f(ushort s) {
  return __uint_as_float(((unsigned int)s) << 16);
}

// parK floats: [0..8191]=lam128_re [8192..16383]=lam128_im [16384..49151]=K[h][d]
__global__ __launch_bounds__(128) void k_prep(
    const float* __restrict__ log_dt, const float* __restrict__ log_A_real,
    const float* __restrict__ A_imag, const float* __restrict__ C_re,
    const float* __restrict__ C_im, float* __restrict__ parK,
    ushort* __restrict__ Mb, ushort* __restrict__ Lb) {
  int h = blockIdx.x;
  int t = threadIdx.x;  // 128
  __shared__ float sdre[32], sdim[32], scdr[32], scdi[32], slr[32], sli[32];
  if (t < 32) {
    int i = h * 32 + t;
    float dt = expf(log_dt[h]);
    float ar = -expf(log_A_real[i]);
    float ai = A_imag[i];
    float dre = ar * dt, dim = ai * dt;
    float er = expf(dre), sn, cs;
    sincosf(dim, &sn, &cs);
    float lr = er * cs, li = er * sn;
    float nr = lr - 1.f, ni = li;
    float inv = 1.f / (ar * ar + ai * ai);
    float tr = (nr * ar + ni * ai) * inv, ti = (ni * ar - nr * ai) * inv;
    float cdr = C_re[i] * tr - C_im[i] * ti;
    float cdi = C_re[i] * ti + C_im[i] * tr;
    sdre[t] = dre; sdim[t] = dim; scdr[t] = cdr; scdi[t] = cdi;
    slr[t] = lr; sli[t] = li;
    float e1 = expf(128.f * dre), ph = 128.f * dim;
    sincosf(ph, &sn, &cs);
    parK[i] = e1 * cs;
    parK[8192 + i] = e1 * sn;
  }
  __syncthreads();
  float ksum = 0.f;
  float tf = (float)t;
  for (int n = 0; n < 32; ++n) {
    float e = expf(tf * sdre[n]);
    float sn, cs;
    sincosf(tf * sdim[n], &sn, &cs);
    float pr = e * cs, pi = e * sn;  // lam^t
    ksum = fmaf(scdr[n], pr, fmaf(-scdi[n], pi, ksum));
    Lb[((size_t)h * 64 + 2 * n) * 128 + (127 - t)] = f2bf(pr);
    Lb[((size_t)h * 64 + 2 * n + 1) * 128 + (127 - t)] = f2bf(pi);
    float plr = pr * slr[n] - pi * sli[n];
    float pli = pr * sli[n] + pi * slr[n];  // lam^{t+1}
    Mb[((size_t)h * 128 + t) * 64 + 2 * n] =
        f2bf(2.f * (scdr[n] * plr - scdi[n] * pli));
    Mb[((size_t)h * 128 + t) * 64 + 2 * n + 1] =
        f2bf(-2.f * (scdr[n] * pli + scdi[n] * plr));
  }
  parK[16384 + h * 128 + t] = 2.f * ksum;
}

// T[h][l'][j] = (l'>=j) ? K[l'-j] + (l'==j)*D[h] : 0   (bf16)
__global__ void k_prep_T(const float* __restrict__ parK,
                         const float* __restrict__ Dp, ushort* __restrict__ T) {
  int idx = blockIdx.x * 256 + threadIdx.x;  // 4,194,304
  int h = idx >> 14;
  int rest = idx & 16383;
  int r = rest >> 7, j = rest & 127;
  int d = r - j;
  float v = 0.f;
  if (d >= 0) {
    v = parK[16384 + (h << 7) + d];
    if (d == 0) v += Dp[h];
  }
  T[idx] = f2bf(v);
}

// Merged: blocks [0,64) = convw (repack W1*g / W2 into fragment order);
// blocks [64,320) = wprep (cs1/b1p). Bodies verbatim from the split kernels.
__global__ __launch_bounds__(256) void k_wcomb(
    const float* __restrict__ W1, const float* __restrict__ W2,
    const float* __restrict__ gam, const float* __restrict__ bet,
    const float* __restrict__ b1, ushort* __restrict__ w1f,
    ushort* __restrict__ w2f, float* __restrict__ cs1,
    float* __restrict__ b1p) {
  __shared__ float ra[256], rb[256];
  if (blockIdx.x < 64) {
    int i = blockIdx.x * 256 + threadIdx.x;  // 16384 threads
    int mat = i >> 13;
    int fi = i & 8191;  // ((kk*16+g)*64 + l)
    int l = fi & 63;
    int gk = fi >> 6;
    int g = gk & 15, kk = gk >> 4;
    int srow = g * 16 + (l & 15);
    int scol = kk * 32 + ((l >> 4) << 3);
    const float* W = mat ? W2 : W1;
    ushort* out = mat ? w2f : w1f;
    short8 v;
#pragma unroll
    for (int e = 0; e < 8; ++e) {
      float w = W[(size_t)srow * 256 + scol + e];
      if (!mat) w *= gam[scol + e];
      v[e] = (short)f2bf(w);
    }
    *(short8*)&out[(size_t)fi * 8] = v;
  } else {
    int o = blockIdx.x - 64, t = threadIdx.x;
    float w = W1[(size_t)o * 256 + t];
    ra[t] = bf2f(f2bf(w * gam[t]));
    rb[t] = w * bet[t];
    __syncthreads();
    for (int s = 128; s > 0; s >>= 1) {
      if (t < s) { ra[t] += ra[t + s]; rb[t] += rb[t + s]; }
      __syncthreads();
    }
    if (t == 0) { cs1[o] = ra[0]; b1p[o] = b1[o] + rb[0]; }
  }
}

// x (B,L,H) fp32 -> U (H, B*L) bf16 (short8 stores)
__global__ __launch_bounds__(256) void k_xT(const float* __restrict__ x,
                                            ushort* __restrict__ U) {
  int blk = blockIdx.x;  // 2048
  int b = blk >> 7;
  int l0 = (blk & 127) << 5;
  int t = threadIdx.x;
  __shared__ float tile[32][257];
#pragma unroll 8
  for (int r = 0; r < 32; ++r)
    tile[r][t] = x[((size_t)b * L_SEQ + l0 + r) * H_DIM + t];
  __syncthreads();
  int hq = t >> 2, ls = (t & 3) * 8;
#pragma unroll
  for (int pass = 0; pass < 4; ++pass) {
    int h = pass * 64 + hq;
    short8 v;
#pragma unroll
    for (int j = 0; j < 8; ++j) v[j] = (short)f2bf(tile[ls + j][h]);
    *(short8*)&U[(size_t)h * 65536 + (size_t)b * L_SEQ + l0 + ls] = v;
  }
}

// FUSED states + scan + y. One block per (h, ct): the chunk scan for the 4
// batches of a ct-tile is closed within the tile, so scanned states never
// touch global. The U tile (Bt) is loaded ONCE and serves both the
// state-MFMA (vs Lb) and phase-2 (T @ u). All f2bf points and fmaf order
// copied verbatim from the split kernels -> bit-identical y.
// LDS: Bt 34 KB + {sts[128][72] + M[128][72] | T[128][136]} 36 KB = 70 KB,
// 2 blocks/CU.
__global__ __launch_bounds__(256, 2) void k_sy(
    const ushort* __restrict__ U, const ushort* __restrict__ Lb,
    const float* __restrict__ parK, const ushort* __restrict__ Mb,
    const ushort* __restrict__ T, ushort* __restrict__ Uo) {
  int wgid = (blockIdx.x & 7) * 128 + (blockIdx.x >> 3);  // bijective, 1024
  int h = wgid >> 2, ct = wgid & 3;
  int t = threadIdx.x;
  int lane = t & 63, wid = t >> 6;
  int wm = wid & 1, wn = wid >> 1;
  int lr_ = lane & 15, lk = (lane >> 4) << 3;
  __shared__ ushort Bt[128][KPAD];                       // U tile, whole kernel
  __shared__ __attribute__((aligned(16))) ushort ovl[18432];  // 36 KiB union
  ushort (*sts)[72] = (ushort(*)[72])ovl;                // states (pad-72)
  ushort (*M_lds)[72] = (ushort(*)[72])(ovl + 128 * 72); // M (pad-72)
  ushort (*T_lds)[136] = (ushort(*)[136])ovl;            // phase-2 overlay
  // ---- stage U tile + M ----
#pragma unroll
  for (int q = 0; q < 8; ++q) {
    int idx = q * 256 + t;
    int cc = idx >> 4, seg = idx & 15;
    int col = ct * 128 + cc;
    int b = col >> 5, c = col & 31;
    *(short8*)&Bt[cc][seg * 8] = *(const short8*)&U[
        (size_t)h * 65536 + (size_t)b * L_SEQ + c * L_C + seg * 8];
  }
#pragma unroll
  for (int q = 0; q < 4; ++q) {
    int idx = q * 256 + t;
    int r = idx >> 3, seg = idx & 7;
    *(short8*)&M_lds[r][seg * 8] =
        *(const short8*)&Mb[((size_t)h * 128 + r) * 64 + seg * 8];
  }
  __syncthreads();
  // ---- state-MFMA: local chunk states (verbatim from k_states) ----
  {
    f32x4 acc2[4][2];
#pragma unroll
    for (int m = 0; m < 4; ++m)
#pragma unroll
      for (int n = 0; n < 2; ++n) acc2[m][n] = (f32x4){0.f, 0.f, 0.f, 0.f};
#pragma unroll
    for (int ks = 0; ks < 4; ++ks) {
      int k0 = ks * 32;
      short8 a[4], bfr[2];
#pragma unroll
      for (int m = 0; m < 4; ++m)
        a[m] = *(const short8*)&Bt[wm * 64 + m * 16 + lr_][k0 + lk];
#pragma unroll
      for (int n = 0; n < 2; ++n)
        bfr[n] = *(const short8*)&Lb[
            ((size_t)h * 64 + wn * 32 + n * 16 + lr_) * 128 + k0 + lk];
#pragma unroll
      for (int m = 0; m < 4; ++m)
#pragma unroll
        for (int n = 0; n < 2; ++n)
          acc2[m][n] = __builtin_amdgcn_mfma_f32_16x16x32_bf16(
              a[m], bfr[n], acc2[m][n], 0, 0, 0);
    }
#pragma unroll
    for (int m = 0; m < 4; ++m)
#pragma unroll
      for (int n = 0; n < 2; ++n)
#pragma unroll
        for (int jj = 0; jj < 4; ++jj) {
          int rowl = wm * 64 + m * 16 + (lane >> 4) * 4 + jj;  // local 0..127
          int col2n = wn * 32 + n * 16 + (lane & 15);
          sts[rowl][col2n] = f2bf(acc2[m][n][jj]);
        }
  }
  __syncthreads();
  // ---- exclusive scan over chunks, in place (verbatim arithmetic) ----
  if (t < 128) {
    int n = t & 31, bl = t >> 5;  // local batch 0..3
    float Lr = parK[h * 32 + n], Li = parK[8192 + h * 32 + n];
    float cr = 0.f, ci = 0.f;
#pragma unroll
    for (int c = 0; c < N_C; ++c) {
      int rowl = bl * 32 + c;
      uint* p = (uint*)&sts[rowl][2 * n];
      uint v = *p;
      float fr = bf2f((ushort)(v & 0xffff));
      float fi = bf2f((ushort)(v >> 16));
      *p = (uint)f2bf(cr) | ((uint)f2bf(ci) << 16);
      float nr_ = fmaf(Lr, cr, fmaf(-Li, ci, fr));
      float ni_ = fmaf(Lr, ci, fmaf(Li, cr, fi));
      cr = nr_; ci = ni_;
    }
  }
  __syncthreads();
  // ---- phase 1: acc = s_init @ M (K=64) ----
  f32x4 acc[4][4];
#pragma unroll
  for (int m = 0; m < 4; ++m)
#pragma unroll
    for (int n = 0; n < 4; ++n) acc[m][n] = (f32x4){0.f, 0.f, 0.f, 0.f};
#pragma unroll
  for (int ks = 0; ks < 2; ++ks) {
    int k0 = ks * 32;
    short8 a[4], bfr[4];
#pragma unroll
    for (int m = 0; m < 4; ++m)
      a[m] = *(const short8*)&sts[wm * 64 + m * 16 + lr_][k0 + lk];
#pragma unroll
    for (int n = 0; n < 4; ++n)
      bfr[n] = *(const short8*)&M_lds[wn * 64 + n * 16 + lr_][k0 + lk];
#pragma unroll
    for (int m = 0; m < 4; ++m)
#pragma unroll
      for (int n = 0; n < 4; ++n)
        acc[m][n] = __builtin_amdgcn_mfma_f32_16x16x32_bf16(a[m], bfr[n],
                                                            acc[m][n], 0, 0, 0);
  }
  __syncthreads();  // sts + M dead; T overlays
  // ---- load T ----
#pragma unroll
  for (int q = 0; q < 8; ++q) {
    int idx = q * 256 + t;
    int r = idx >> 4, seg = idx & 15;
    *(short8*)&T_lds[r][seg * 8] =
        *(const short8*)&T[((size_t)h * 128 + r) * 128 + seg * 8];
  }
  __syncthreads();
  // ---- phase 2: acc += u @ T (K=128) ----
#pragma unroll
  for (int ks = 0; ks < 4; ++ks) {
    int k0 = ks * 32;
    short8 a[4], bfr[4];
#pragma unroll
    for (int m = 0; m < 4; ++m)
      a[m] = *(const short8*)&Bt[wm * 64 + m * 16 + lr_][k0 + lk];
#pragma unroll
    for (int n = 0; n < 4; ++n)
      bfr[n] = *(const short8*)&T_lds[wn * 64 + n * 16 + lr_][k0 + lk];
#pragma unroll
    for (int m = 0; m < 4; ++m)
#pragma unroll
      for (int n = 0; n < 4; ++n)
        acc[m][n] = __builtin_amdgcn_mfma_f32_16x16x32_bf16(a[m], bfr[n],
                                                            acc[m][n], 0, 0, 0);
  }
  // ---- stage y into Bt (dead), vectorized short8 store (in place) ----
  __syncthreads();
#pragma unroll
  for (int m = 0; m < 4; ++m) {
    int rowl = wm * 64 + m * 16 + (lane >> 4) * 4;
#pragma unroll
    for (int jj = 0; jj < 4; ++jj) {
      int row = rowl + jj;
#pragma unroll
      for (int n = 0; n < 4; ++n) {
        int lp = wn * 64 + n * 16 + (lane & 15);
        Bt[row][lp] = f2bf(acc[m][n][jj]);
      }
    }
  }
  __syncthreads();
#pragma unroll
  for (int q = 0; q < 8; ++q) {
    int idx = q * 256 + t;
    int r = idx >> 4, seg = idx & 15;
    int col = ct * 128 + r;
    int b = col >> 5, c = col & 31;
    *(short8*)&Uo[(size_t)h * 65536 + (size_t)b * L_SEQ + c * L_C + seg * 8] =
        *(const short8*)&Bt[r][seg * 8];
  }
}

// Fused LN + MLP (round-0 version: 128-row, 512 threads, fused transpose+LN
// — the best-measured k_mlp structure at ~49.8 us).
__global__ __launch_bounds__(512, 4) void k_mlp(
    const ushort* __restrict__ U, const ushort* __restrict__ w1f,
    const ushort* __restrict__ w2f, const float* __restrict__ cs1,
    const float* __restrict__ b1p, const float* __restrict__ b2,
    const float* __restrict__ xres, float* __restrict__ outp) {
  int m0 = blockIdx.x << 7;  // 512 blocks x 128 rows of (B*L)
  int t = threadIdx.x;       // 512 threads = 8 waves (2M x 4N)
  int lane = t & 63, wid = t >> 6;
  int wm = wid & 1, wn = wid >> 1;
  int lr_ = lane & 15, lk = (lane >> 4) << 3;
  __shared__ ushort smem[33792];  // yt[128][264] swizzled; c_s overlays [0,32768)
  __shared__ float redA[128][4], redB[128][4];
  __shared__ float mu_s[128], rs_s[128];
  // ---- transpose load: U[h][m0+m] -> yt[m][h ^ ((m>>3&7)<<3)] ----
  {
    int hseg = t >> 4, l16 = t & 15;
    int sw = (l16 & 7) << 3;
#pragma unroll
    for (int p = 0; p < 8; ++p) {
      int h = p * 32 + hseg;
      short8 v = *(const short8*)&U[(size_t)h * 65536 + m0 + l16 * 8];
      int hx = h ^ sw;
#pragma unroll
      for (int e = 0; e < 8; ++e)
        smem[(l16 * 8 + e) * 264 + hx] = (ushort)v[e];
    }
  }
  __syncthreads();
  // ---- LN stats ----
  {
    int rl = t >> 2, q = (t & 3) << 6;
    float s = 0.f, s2 = 0.f;
#pragma unroll
    for (int e = 0; e < 64; e += 8) {
      short8 v = *(const short8*)&smem[rl * 264 + q + e];
#pragma unroll
      for (int j = 0; j < 8; ++j) {
        float f = bf2f((ushort)v[j]);
        s += f;
        s2 = fmaf(f, f, s2);
      }
    }
    redA[rl][t & 3] = s;
    redB[rl][t & 3] = s2;
  }
  __syncthreads();
  if (t < 128) {
    float ss = redA[t][0] + redA[t][1] + redA[t][2] + redA[t][3];
    float ss2 = redB[t][0] + redB[t][1] + redB[t][2] + redB[t][3];
    float mu = ss * (1.f / 256.f);
    float var = fmaf(ss2, 1.f / 256.f, -mu * mu);
    mu_s[t] = mu;
    rs_s[t] = rsqrtf(var + 1e-5f);
  }
  __syncthreads();
  // ---- phase 1: acc = y @ (W1*g)^T ----
  f32x4 acc[4][4];
#pragma unroll
  for (int m = 0; m < 4; ++m)
#pragma unroll
    for (int n = 0; n < 4; ++n) acc[m][n] = (f32x4){0.f, 0.f, 0.f, 0.f};
#pragma unroll
  for (int kabs = 0; kabs < 8; ++kabs) {
    short8 af[4], bfr[4];
#pragma unroll
    for (int n = 0; n < 4; ++n)
      bfr[n] = *(const short8*)&w1f[(((size_t)kabs * 16 + wn * 4 + n) * 64 +
                                     lane) * 8];
#pragma unroll
    for (int m = 0; m < 4; ++m) {
      int row = wm * 64 + m * 16 + lr_;
      int sw = ((row >> 3) & 7) << 3;
      af[m] = *(const short8*)&smem[row * 264 + ((kabs * 32 + lk) ^ sw)];
    }
#pragma unroll
    for (int m = 0; m < 4; ++m)
#pragma unroll
      for (int n = 0; n < 4; ++n)
        acc[m][n] = __builtin_amdgcn_mfma_f32_16x16x32_bf16(af[m], bfr[n],
                                                            acc[m][n], 0, 0, 0);
  }
  __syncthreads();  // yt dead; c_s overlays
  // ---- epilogue 1: LN-correct + bias + relu -> bf16 -> swizzled c_s ----
  int prow = (lane >> 4) << 2;
  int pcol = lane & 15;
#pragma unroll
  for (int n = 0; n < 4; ++n) {
    int gcol = wn * 64 + n * 16 + pcol;
    float c1v = cs1[gcol], b1v = b1p[gcol];
#pragma unroll
    for (int m = 0; m < 4; ++m) {
      int rbase = wm * 64 + m * 16 + prow;
#pragma unroll
      for (int j = 0; j < 4; ++j) {
        int row = rbase + j;
        float v = fmaxf(
            fmaf(rs_s[row], acc[m][n][j] - mu_s[row] * c1v, b1v), 0.f);
        int byte = ((row << 9) + (gcol << 1)) ^ ((row & 7) << 4);
        smem[byte >> 1] = f2bf(v);
        acc[m][n][j] = 0.f;  // re-zero for phase 2
      }
    }
  }
  __syncthreads();
  // ---- phase 2: acc = C1 @ W2^T ----
#pragma unroll
  for (int kabs = 0; kabs < 8; ++kabs) {
    short8 af[4], bfr[4];
#pragma unroll
    for (int n = 0; n < 4; ++n)
      bfr[n] = *(const short8*)&w2f[(((size_t)kabs * 16 + wn * 4 + n) * 64 +
                                     lane) * 8];
#pragma unroll
    for (int m = 0; m < 4; ++m) {
      int row = wm * 64 + m * 16 + lr_;
      int byte = ((row << 9) + ((kabs * 32 + lk) << 1)) ^ ((row & 7) << 4);
      af[m] = *(const short8*)&smem[byte >> 1];
    }
#pragma unroll
    for (int m = 0; m < 4; ++m)
#pragma unroll
      for (int n = 0; n < 4; ++n)
        acc[m][n] = __builtin_amdgcn_mfma_f32_16x16x32_bf16(af[m], bfr[n],
                                                            acc[m][n], 0, 0, 0);
  }
  // ---- epilogue 2: bias+relu + residual, fp32 out (direct) ----
  float bv2[4];
#pragma unroll
  for (int n = 0; n < 4; ++n) bv2[n] = b2[wn * 64 + n * 16 + pcol];
#pragma unroll
  for (int m = 0; m < 4; ++m) {
#pragma unroll
    for (int j = 0; j < 4; ++j) {
      int grow = m0 + wm * 64 + m * 16 + prow + j;
      size_t rb = (size_t)grow * 256;
#pragma unroll
      for (int n = 0; n < 4; ++n) {
        int gcol = wn * 64 + n * 16 + pcol;
        float v = fmaxf(acc[m][n][j] + bv2[n], 0.f);
        outp[rb + gcol] = xres[rb + gcol] + v;
      }
    }
  }
}

extern "C" void kernel_launch(void* const* d_in, const int* in_sizes, int n_in,
                              void* d_out, int out_size, void* d_ws, size_t ws_size,
                              hipStream_t stream) {
  const float* x          = (const float*)d_in[0];
  const float* log_dt     = (const float*)d_in[1];
  const float* log_A_real = (const float*)d_in[2];
  const float* A_imag     = (const float*)d_in[3];
  const float* C_re       = (const float*)d_in[4];
  const float* C_im       = (const float*)d_in[5];
  const float* Dp         = (const float*)d_in[6];
  const float* ln_g       = (const float*)d_in[7];
  const float* ln_b       = (const float*)d_in[8];
  const float* W1         = (const float*)d_in[9];
  const float* b1         = (const float*)d_in[10];
  const float* W2         = (const float*)d_in[11];
  const float* b2         = (const float*)d_in[12];

  char* ws = (char*)d_ws;
  float* parK = (float*)ws;                       // 192 KiB
  float* cs1  = (float*)(ws + 0x30000);           // 1 KiB
  float* b1p  = (float*)(ws + 0x30400);           // 1 KiB
  ushort* w1f = (ushort*)(ws + 0x40000);          // 128 KiB (fragment order)
  ushort* w2f = (ushort*)(ws + 0x60000);          // 128 KiB (fragment order)
  ushort* Mb  = (ushort*)(ws + 0x80000);          // 4 MiB
  ushort* Lb  = (ushort*)(ws + 0x480000);         // 4 MiB
  ushort* Tb  = (ushort*)(ws + 0x880000);         // 8 MiB
  ushort* U   = (ushort*)(ws + 0x2080000);        // 32 MiB (y written in place)

  k_prep<<<256, 128, 0, stream>>>(log_dt, log_A_real, A_imag, C_re, C_im,
                                  parK, Mb, Lb);
  k_prep_T<<<16384, 256, 0, stream>>>(parK, Dp, Tb);
  k_wcomb<<<320, 256, 0, stream>>>(W1, W2, ln_g, ln_b, b1, w1f, w2f, cs1, b1p);
  k_xT<<<2048, 256, 0, stream>>>(x, U);
  k_sy<<<1024, 256, 0, stream>>>(U, Lb, parK, Mb, Tb, U);
  k_mlp<<<512, 512, 0, stream>>>(U, w1f, w2f, cs1, b1p, b2, x,
                                 (float*)d_out);
}

// Round 5
// 93.557 us; speedup vs baseline: 1.4812x; 1.1822x over previous
//
#include <hip/hip_runtime.h>

#define H_DIM 256
#define N2D   32
#define L_SEQ 4096
#define B_SZ  16
#define L_C   128
#define N_C   32
#define KPAD  136

typedef short short8 __attribute__((ext_vector_type(8)));
typedef short short4v __attribute__((ext_vector_type(4)));
typedef float f32x4  __attribute__((ext_vector_type(4)));
typedef unsigned short ushort;

__device__ __forceinline__ ushort f2bf(float f) {
  unsigned int u = __float_as_uint(f);
  u = (u + 0x7fffu + ((u >> 16) & 1u)) >> 16;
  return (ushort)u;
}
__device__ __forceinline__ float bf2f(ushort s) {
  return __uint_as_float(((unsigned int)s) << 16);
}

// Merged front-end, block-range dispatch (2624 blocks x 256 thr):
//   [0,256)    : k_prep body (h = bid), heavy transcendental -> launch first
//   [256,576)  : w-prep (convw <64 blocks, wprep else). W2 repacked with
//                PERMUTED output columns: srow = (g>>2)*64 + (l&15)*4 + (g&3)
//                so k_mlp epilogue-2 lanes own 4 consecutive cols (float4 IO).
//   [576,2624) : x transpose (B,L,H) fp32 -> U (H, B*L) bf16
__global__ __launch_bounds__(256) void k_front(
    const float* __restrict__ x, const float* __restrict__ log_dt,
    const float* __restrict__ log_A_real, const float* __restrict__ A_imag,
    const float* __restrict__ C_re, const float* __restrict__ C_im,
    const float* __restrict__ W1, const float* __restrict__ W2,
    const float* __restrict__ gam, const float* __restrict__ bet,
    const float* __restrict__ b1, float* __restrict__ parK,
    ushort* __restrict__ Mb, ushort* __restrict__ Lb,
    ushort* __restrict__ w1f, ushort* __restrict__ w2f,
    float* __restrict__ cs1, float* __restrict__ b1p,
    ushort* __restrict__ U) {
  int bid = blockIdx.x;
  int t = threadIdx.x;
  if (bid < 256) {
    // ---- k_prep (verbatim, 256 thr: t<128 active in main loop) ----
    int h = bid;
    __shared__ float sdre[32], sdim[32], scdr[32], scdi[32], slr[32], sli[32];
    if (t < 32) {
      int i = h * 32 + t;
      float dt = expf(log_dt[h]);
      float ar = -expf(log_A_real[i]);
      float ai = A_imag[i];
      float dre = ar * dt, dim = ai * dt;
      float er = expf(dre), sn, cs;
      sincosf(dim, &sn, &cs);
      float lr = er * cs, li = er * sn;
      float nr = lr - 1.f, ni = li;
      float inv = 1.f / (ar * ar + ai * ai);
      float tr = (nr * ar + ni * ai) * inv, ti = (ni * ar - nr * ai) * inv;
      float cdr = C_re[i] * tr - C_im[i] * ti;
      float cdi = C_re[i] * ti + C_im[i] * tr;
      sdre[t] = dre; sdim[t] = dim; scdr[t] = cdr; scdi[t] = cdi;
      slr[t] = lr; sli[t] = li;
      float e1 = expf(128.f * dre), ph = 128.f * dim;
      sincosf(ph, &sn, &cs);
      parK[i] = e1 * cs;
      parK[8192 + i] = e1 * sn;
    }
    __syncthreads();
    if (t < 128) {
      float ksum = 0.f;
      float tf = (float)t;
      for (int n = 0; n < 32; ++n) {
        float e = expf(tf * sdre[n]);
        float sn, cs;
        sincosf(tf * sdim[n], &sn, &cs);
        float pr = e * cs, pi = e * sn;  // lam^t
        ksum = fmaf(scdr[n], pr, fmaf(-scdi[n], pi, ksum));
        Lb[((size_t)h * 64 + 2 * n) * 128 + (127 - t)] = f2bf(pr);
        Lb[((size_t)h * 64 + 2 * n + 1) * 128 + (127 - t)] = f2bf(pi);
        float plr = pr * slr[n] - pi * sli[n];
        float pli = pr * sli[n] + pi * slr[n];  // lam^{t+1}
        Mb[((size_t)h * 128 + t) * 64 + 2 * n] =
            f2bf(2.f * (scdr[n] * plr - scdi[n] * pli));
        Mb[((size_t)h * 128 + t) * 64 + 2 * n + 1] =
            f2bf(-2.f * (scdr[n] * pli + scdi[n] * plr));
      }
      parK[16384 + h * 128 + t] = 2.f * ksum;
    }
  } else if (bid < 576) {
    int wb = bid - 256;
    if (wb < 64) {
      // ---- convw: fragment repack (W2 with permuted output cols) ----
      int i = wb * 256 + t;  // 16384 threads
      int mat = i >> 13;
      int fi = i & 8191;  // ((kk*16+g)*64 + l)
      int l = fi & 63;
      int gk = fi >> 6;
      int g = gk & 15, kk = gk >> 4;
      int srow = mat ? ((g >> 2) * 64 + (l & 15) * 4 + (g & 3))
                     : (g * 16 + (l & 15));
      int scol = kk * 32 + ((l >> 4) << 3);
      const float* W = mat ? W2 : W1;
      ushort* out = mat ? w2f : w1f;
      short8 v;
#pragma unroll
      for (int e = 0; e < 8; ++e) {
        float w = W[(size_t)srow * 256 + scol + e];
        if (!mat) w *= gam[scol + e];
        v[e] = (short)f2bf(w);
      }
      *(short8*)&out[(size_t)fi * 8] = v;
    } else {
      // ---- wprep: cs1/b1p ----
      int o = wb - 64;
      __shared__ float ra[256], rb[256];
      float w = W1[(size_t)o * 256 + t];
      ra[t] = bf2f(f2bf(w * gam[t]));
      rb[t] = w * bet[t];
      __syncthreads();
      for (int s = 128; s > 0; s >>= 1) {
        if (t < s) { ra[t] += ra[t + s]; rb[t] += rb[t + s]; }
        __syncthreads();
      }
      if (t == 0) { cs1[o] = ra[0]; b1p[o] = b1[o] + rb[0]; }
    }
  } else {
    // ---- xT: x -> U (bf16, short8 stores) ----
    int blk = bid - 576;  // 2048
    int b = blk >> 7;
    int l0 = (blk & 127) << 5;
    __shared__ float tile[32][257];
#pragma unroll 8
    for (int r = 0; r < 32; ++r)
      tile[r][t] = x[((size_t)b * L_SEQ + l0 + r) * H_DIM + t];
    __syncthreads();
    int hq = t >> 2, ls = (t & 3) * 8;
#pragma unroll
    for (int pass = 0; pass < 4; ++pass) {
      int h = pass * 64 + hq;
      short8 v;
#pragma unroll
      for (int j = 0; j < 8; ++j) v[j] = (short)f2bf(tile[ls + j][h]);
      *(short8*)&U[(size_t)h * 65536 + (size_t)b * L_SEQ + l0 + ls] = v;
    }
  }
}

// FUSED states + scan + y. One block per (h, ct). T is now COMPUTED in-LDS
// from the K row (parK[16384+h*128+..], +D on diagonal) — element formula
// verbatim from the old k_prep_T -> bit-identical y; kills the k_prep_T
// kernel and 16 MB of T write+read traffic.
__global__ __launch_bounds__(256, 2) void k_sy(
    const ushort* __restrict__ U, const ushort* __restrict__ Lb,
    const float* __restrict__ parK, const ushort* __restrict__ Mb,
    const float* __restrict__ Dp, ushort* __restrict__ Uo) {
  int wgid = (blockIdx.x & 7) * 128 + (blockIdx.x >> 3);  // bijective, 1024
  int h = wgid >> 2, ct = wgid & 3;
  int t = threadIdx.x;
  int lane = t & 63, wid = t >> 6;
  int wm = wid & 1, wn = wid >> 1;
  int lr_ = lane & 15, lk = (lane >> 4) << 3;
  __shared__ ushort Bt[128][KPAD];                       // U tile, whole kernel
  __shared__ __attribute__((aligned(16))) ushort ovl[18432];  // 36 KiB union
  __shared__ float Krow[128];
  ushort (*sts)[72] = (ushort(*)[72])ovl;                // states (pad-72)
  ushort (*M_lds)[72] = (ushort(*)[72])(ovl + 128 * 72); // M (pad-72)
  ushort (*T_lds)[136] = (ushort(*)[136])ovl;            // phase-2 overlay
  // ---- stage U tile + M + K row ----
  if (t < 128) {
    float kv = parK[16384 + h * 128 + t];
    if (t == 0) kv += Dp[h];
    Krow[t] = kv;
  }
#pragma unroll
  for (int q = 0; q < 8; ++q) {
    int idx = q * 256 + t;
    int cc = idx >> 4, seg = idx & 15;
    int col = ct * 128 + cc;
    int b = col >> 5, c = col & 31;
    *(short8*)&Bt[cc][seg * 8] = *(const short8*)&U[
        (size_t)h * 65536 + (size_t)b * L_SEQ + c * L_C + seg * 8];
  }
#pragma unroll
  for (int q = 0; q < 4; ++q) {
    int idx = q * 256 + t;
    int r = idx >> 3, seg = idx & 7;
    *(short8*)&M_lds[r][seg * 8] =
        *(const short8*)&Mb[((size_t)h * 128 + r) * 64 + seg * 8];
  }
  __syncthreads();
  // ---- state-MFMA: local chunk states ----
  {
    f32x4 acc2[4][2];
#pragma unroll
    for (int m = 0; m < 4; ++m)
#pragma unroll
      for (int n = 0; n < 2; ++n) acc2[m][n] = (f32x4){0.f, 0.f, 0.f, 0.f};
#pragma unroll
    for (int ks = 0; ks < 4; ++ks) {
      int k0 = ks * 32;
      short8 a[4], bfr[2];
#pragma unroll
      for (int m = 0; m < 4; ++m)
        a[m] = *(const short8*)&Bt[wm * 64 + m * 16 + lr_][k0 + lk];
#pragma unroll
      for (int n = 0; n < 2; ++n)
        bfr[n] = *(const short8*)&Lb[
            ((size_t)h * 64 + wn * 32 + n * 16 + lr_) * 128 + k0 + lk];
#pragma unroll
      for (int m = 0; m < 4; ++m)
#pragma unroll
        for (int n = 0; n < 2; ++n)
          acc2[m][n] = __builtin_amdgcn_mfma_f32_16x16x32_bf16(
              a[m], bfr[n], acc2[m][n], 0, 0, 0);
    }
#pragma unroll
    for (int m = 0; m < 4; ++m)
#pragma unroll
      for (int n = 0; n < 2; ++n)
#pragma unroll
        for (int jj = 0; jj < 4; ++jj) {
          int rowl = wm * 64 + m * 16 + (lane >> 4) * 4 + jj;  // local 0..127
          int col2n = wn * 32 + n * 16 + (lane & 15);
          sts[rowl][col2n] = f2bf(acc2[m][n][jj]);
        }
  }
  __syncthreads();
  // ---- exclusive scan over chunks, in place (verbatim arithmetic) ----
  if (t < 128) {
    int n = t & 31, bl = t >> 5;  // local batch 0..3
    float Lr = parK[h * 32 + n], Li = parK[8192 + h * 32 + n];
    float cr = 0.f, ci = 0.f;
#pragma unroll
    for (int c = 0; c < N_C; ++c) {
      int rowl = bl * 32 + c;
      uint* p = (uint*)&sts[rowl][2 * n];
      uint v = *p;
      float fr = bf2f((ushort)(v & 0xffff));
      float fi = bf2f((ushort)(v >> 16));
      *p = (uint)f2bf(cr) | ((uint)f2bf(ci) << 16);
      float nr_ = fmaf(Lr, cr, fmaf(-Li, ci, fr));
      float ni_ = fmaf(Lr, ci, fmaf(Li, cr, fi));
      cr = nr_; ci = ni_;
    }
  }
  __syncthreads();
  // ---- phase 1: acc = s_init @ M (K=64) ----
  f32x4 acc[4][4];
#pragma unroll
  for (int m = 0; m < 4; ++m)
#pragma unroll
    for (int n = 0; n < 4; ++n) acc[m][n] = (f32x4){0.f, 0.f, 0.f, 0.f};
#pragma unroll
  for (int ks = 0; ks < 2; ++ks) {
    int k0 = ks * 32;
    short8 a[4], bfr[4];
#pragma unroll
    for (int m = 0; m < 4; ++m)
      a[m] = *(const short8*)&sts[wm * 64 + m * 16 + lr_][k0 + lk];
#pragma unroll
    for (int n = 0; n < 4; ++n)
      bfr[n] = *(const short8*)&M_lds[wn * 64 + n * 16 + lr_][k0 + lk];
#pragma unroll
    for (int m = 0; m < 4; ++m)
#pragma unroll
      for (int n = 0; n < 4; ++n)
        acc[m][n] = __builtin_amdgcn_mfma_f32_16x16x32_bf16(a[m], bfr[n],
                                                            acc[m][n], 0, 0, 0);
  }
  __syncthreads();  // sts + M dead; T overlays
  // ---- build T in LDS from Krow: T[r][j] = (r>=j)? K[r-j] (+D at r==j) : 0 ----
#pragma unroll
  for (int q = 0; q < 8; ++q) {
    int idx = q * 256 + t;
    int r = idx >> 4, seg = idx & 15;
    short8 v;
#pragma unroll
    for (int e = 0; e < 8; ++e) {
      int d = r - (seg * 8 + e);
      float f = (d >= 0) ? Krow[d] : 0.f;
      v[e] = (short)f2bf(f);
    }
    *(short8*)&T_lds[r][seg * 8] = v;
  }
  __syncthreads();
  // ---- phase 2: acc += u @ T (K=128) ----
#pragma unroll
  for (int ks = 0; ks < 4; ++ks) {
    int k0 = ks * 32;
    short8 a[4], bfr[4];
#pragma unroll
    for (int m = 0; m < 4; ++m)
      a[m] = *(const short8*)&Bt[wm * 64 + m * 16 + lr_][k0 + lk];
#pragma unroll
    for (int n = 0; n < 4; ++n)
      bfr[n] = *(const short8*)&T_lds[wn * 64 + n * 16 + lr_][k0 + lk];
#pragma unroll
    for (int m = 0; m < 4; ++m)
#pragma unroll
      for (int n = 0; n < 4; ++n)
        acc[m][n] = __builtin_amdgcn_mfma_f32_16x16x32_bf16(a[m], bfr[n],
                                                            acc[m][n], 0, 0, 0);
  }
  // ---- stage y into Bt (dead), vectorized short8 store (in place) ----
  __syncthreads();
#pragma unroll
  for (int m = 0; m < 4; ++m) {
    int rowl = wm * 64 + m * 16 + (lane >> 4) * 4;
#pragma unroll
    for (int jj = 0; jj < 4; ++jj) {
      int row = rowl + jj;
#pragma unroll
      for (int n = 0; n < 4; ++n) {
        int lp = wn * 64 + n * 16 + (lane & 15);
        Bt[row][lp] = f2bf(acc[m][n][jj]);
      }
    }
  }
  __syncthreads();
#pragma unroll
  for (int q = 0; q < 8; ++q) {
    int idx = q * 256 + t;
    int r = idx >> 4, seg = idx & 15;
    int col = ct * 128 + r;
    int b = col >> 5, c = col & 31;
    *(short8*)&Uo[(size_t)h * 65536 + (size_t)b * L_SEQ + c * L_C + seg * 8] =
        *(const short8*)&Bt[r][seg * 8];
  }
}

// Fused LN + MLP (round-0 structure) + PERMUTED-W2 epilogue: each lane owns
// 4 consecutive output cols -> float4 xres/out/b2 (kills the 1.44x write
// amplification of the old scalar 4B stores).
__global__ __launch_bounds__(512, 4) void k_mlp(
    const ushort* __restrict__ U, const ushort* __restrict__ w1f,
    const ushort* __restrict__ w2f, const float* __restrict__ cs1,
    const float* __restrict__ b1p, const float* __restrict__ b2,
    const float* __restrict__ xres, float* __restrict__ outp) {
  int m0 = blockIdx.x << 7;  // 512 blocks x 128 rows of (B*L)
  int t = threadIdx.x;       // 512 threads = 8 waves (2M x 4N)
  int lane = t & 63, wid = t >> 6;
  int wm = wid & 1, wn = wid >> 1;
  int lr_ = lane & 15, lk = (lane >> 4) << 3;
  __shared__ ushort smem[33792];  // yt[128][264] swizzled; c_s overlays [0,32768)
  __shared__ float redA[128][4], redB[128][4];
  __shared__ float mu_s[128], rs_s[128];
  // ---- transpose load: U[h][m0+m] -> yt[m][h ^ ((m>>3&7)<<3)] ----
  {
    int hseg = t >> 4, l16 = t & 15;
    int sw = (l16 & 7) << 3;
#pragma unroll
    for (int p = 0; p < 8; ++p) {
      int h = p * 32 + hseg;
      short8 v = *(const short8*)&U[(size_t)h * 65536 + m0 + l16 * 8];
      int hx = h ^ sw;
#pragma unroll
      for (int e = 0; e < 8; ++e)
        smem[(l16 * 8 + e) * 264 + hx] = (ushort)v[e];
    }
  }
  __syncthreads();
  // ---- LN stats ----
  {
    int rl = t >> 2, q = (t & 3) << 6;
    float s = 0.f, s2 = 0.f;
#pragma unroll
    for (int e = 0; e < 64; e += 8) {
      short8 v = *(const short8*)&smem[rl * 264 + q + e];
#pragma unroll
      for (int j = 0; j < 8; ++j) {
        float f = bf2f((ushort)v[j]);
        s += f;
        s2 = fmaf(f, f, s2);
      }
    }
    redA[rl][t & 3] = s;
    redB[rl][t & 3] = s2;
  }
  __syncthreads();
  if (t < 128) {
    float ss = redA[t][0] + redA[t][1] + redA[t][2] + redA[t][3];
    float ss2 = redB[t][0] + redB[t][1] + redB[t][2] + redB[t][3];
    float mu = ss * (1.f / 256.f);
    float var = fmaf(ss2, 1.f / 256.f, -mu * mu);
    mu_s[t] = mu;
    rs_s[t] = rsqrtf(var + 1e-5f);
  }
  __syncthreads();
  // ---- phase 1: acc = y @ (W1*g)^T ----
  f32x4 acc[4][4];
#pragma unroll
  for (int m = 0; m < 4; ++m)
#pragma unroll
    for (int n = 0; n < 4; ++n) acc[m][n] = (f32x4){0.f, 0.f, 0.f, 0.f};
#pragma unroll
  for (int kabs = 0; kabs < 8; ++kabs) {
    short8 af[4], bfr[4];
#pragma unroll
    for (int n = 0; n < 4; ++n)
      bfr[n] = *(const short8*)&w1f[(((size_t)kabs * 16 + wn * 4 + n) * 64 +
                                     lane) * 8];
#pragma unroll
    for (int m = 0; m < 4; ++m) {
      int row = wm * 64 + m * 16 + lr_;
      int sw = ((row >> 3) & 7) << 3;
      af[m] = *(const short8*)&smem[row * 264 + ((kabs * 32 + lk) ^ sw)];
    }
#pragma unroll
    for (int m = 0; m < 4; ++m)
#pragma unroll
      for (int n = 0; n < 4; ++n)
        acc[m][n] = __builtin_amdgcn_mfma_f32_16x16x32_bf16(af[m], bfr[n],
                                                            acc[m][n], 0, 0, 0);
  }
  __syncthreads();  // yt dead; c_s overlays
  // ---- epilogue 1: LN-correct + bias + relu -> bf16 -> swizzled c_s ----
  int prow = (lane >> 4) << 2;
  int pcol = lane & 15;
#pragma unroll
  for (int n = 0; n < 4; ++n) {
    int gcol = wn * 64 + n * 16 + pcol;
    float c1v = cs1[gcol], b1v = b1p[gcol];
#pragma unroll
    for (int m = 0; m < 4; ++m) {
      int rbase = wm * 64 + m * 16 + prow;
#pragma unroll
      for (int j = 0; j < 4; ++j) {
        int row = rbase + j;
        float v = fmaxf(
            fmaf(rs_s[row], acc[m][n][j] - mu_s[row] * c1v, b1v), 0.f);
        int byte = ((row << 9) + (gcol << 1)) ^ ((row & 7) << 4);
        smem[byte >> 1] = f2bf(v);
        acc[m][n][j] = 0.f;  // re-zero for phase 2
      }
    }
  }
  __syncthreads();
  // ---- phase 2: acc = C1 @ W2^T (W2 output cols permuted at pack time) ----
#pragma unroll
  for (int kabs = 0; kabs < 8; ++kabs) {
    short8 af[4], bfr[4];
#pragma unroll
    for (int n = 0; n < 4; ++n)
      bfr[n] = *(const short8*)&w2f[(((size_t)kabs * 16 + wn * 4 + n) * 64 +
                                     lane) * 8];
#pragma unroll
    for (int m = 0; m < 4; ++m) {
      int row = wm * 64 + m * 16 + lr_;
      int byte = ((row << 9) + ((kabs * 32 + lk) << 1)) ^ ((row & 7) << 4);
      af[m] = *(const short8*)&smem[byte >> 1];
    }
#pragma unroll
    for (int m = 0; m < 4; ++m)
#pragma unroll
      for (int n = 0; n < 4; ++n)
        acc[m][n] = __builtin_amdgcn_mfma_f32_16x16x32_bf16(af[m], bfr[n],
                                                            acc[m][n], 0, 0, 0);
  }
  // ---- epilogue 2: lane owns cols wn*64 + pcol*4 + {0..3} -> float4 IO ----
  f32x4 bv2q = *(const f32x4*)&b2[wn * 64 + pcol * 4];
#pragma unroll
  for (int m = 0; m < 4; ++m) {
#pragma unroll
    for (int j = 0; j < 4; ++j) {
      int grow = m0 + wm * 64 + m * 16 + prow + j;
      size_t base = (size_t)grow * 256 + wn * 64 + pcol * 4;
      f32x4 xr = *(const f32x4*)&xres[base];
      f32x4 o;
#pragma unroll
      for (int n = 0; n < 4; ++n)
        o[n] = xr[n] + fmaxf(acc[m][n][j] + bv2q[n], 0.f);
      *(f32x4*)&outp[base] = o;
    }
  }
}

extern "C" void kernel_launch(void* const* d_in, const int* in_sizes, int n_in,
                              void* d_out, int out_size, void* d_ws, size_t ws_size,
                              hipStream_t stream) {
  const float* x          = (const float*)d_in[0];
  const float* log_dt     = (const float*)d_in[1];
  const float* log_A_real = (const float*)d_in[2];
  const float* A_imag     = (const float*)d_in[3];
  const float* C_re       = (const float*)d_in[4];
  const float* C_im       = (const float*)d_in[5];
  const float* Dp         = (const float*)d_in[6];
  const float* ln_g       = (const float*)d_in[7];
  const float* ln_b       = (const float*)d_in[8];
  const float* W1         = (const float*)d_in[9];
  const float* b1         = (const float*)d_in[10];
  const float* W2         = (const float*)d_in[11];
  const float* b2         = (const float*)d_in[12];

  char* ws = (char*)d_ws;
  float* parK = (float*)ws;                       // 192 KiB
  float* cs1  = (float*)(ws + 0x30000);           // 1 KiB
  float* b1p  = (float*)(ws + 0x30400);           // 1 KiB
  ushort* w1f = (ushort*)(ws + 0x40000);          // 128 KiB (fragment order)
  ushort* w2f = (ushort*)(ws + 0x60000);          // 128 KiB (fragment order)
  ushort* Mb  = (ushort*)(ws + 0x80000);          // 4 MiB
  ushort* Lb  = (ushort*)(ws + 0x480000);         // 4 MiB
  ushort* U   = (ushort*)(ws + 0x2080000);        // 32 MiB (y written in place)

  k_front<<<2624, 256, 0, stream>>>(x, log_dt, log_A_real, A_imag, C_re, C_im,
                                    W1, W2, ln_g, ln_b, b1, parK, Mb, Lb,
                                    w1f, w2f, cs1, b1p, U);
  k_sy<<<1024, 256, 0, stream>>>(U, Lb, parK, Mb, Dp, U);
  k_mlp<<<512, 512, 0, stream>>>(U, w1f, w2f, cs1, b1p, b2, x,
                                 (float*)d_out);
}